// Round 5
// baseline (561.038 us; speedup 1.0000x reference)
//
#include <hip/hip_runtime.h>

typedef unsigned short u16;
typedef __attribute__((ext_vector_type(8))) short short8;    // 8 bf16 (4 VGPRs)
typedef __attribute__((ext_vector_type(4))) float f32x4;
typedef __attribute__((ext_vector_type(4))) unsigned short u16x4;

typedef __attribute__((address_space(1))) void as1_void;
typedef __attribute__((address_space(3))) void as3_void;

// async global->LDS, 16B per lane; LDS dest = wave-uniform base + lane*16
__device__ __forceinline__ void gld16(const u16* g, u16* l) {
  __builtin_amdgcn_global_load_lds((as1_void*)g, (as3_void*)l, 16, 0, 0);
}

__device__ __forceinline__ u16 f2bf(float f) {
  unsigned u = __float_as_uint(f);
  u += 0x7fffu + ((u >> 16) & 1u);   // RNE
  return (u16)(u >> 16);
}

// ---------------- fused prep: cvt x (x4) + W_eff + cvt wo ----------------
// blocks [0,3072): x cvt vectorized; [3072,12288): weff rows 0..2303, wob rows 2304..3071
__global__ void prep_all(const float* __restrict__ x, u16* __restrict__ xb,
                         const float* __restrict__ wq, const float* __restrict__ wk, const float* __restrict__ wv,
                         const float* __restrict__ dq, const float* __restrict__ uq,
                         const float* __restrict__ dk, const float* __restrict__ uk,
                         const float* __restrict__ dv, const float* __restrict__ uv,
                         const float* __restrict__ wo, u16* __restrict__ weff, u16* __restrict__ wob) {
  int bid = blockIdx.x;
  if (bid < 3072) {
    int i = bid * 256 + threadIdx.x;          // < 786432
    f32x4 f = *(const f32x4*)(x + (size_t)i * 4);
    u16x4 o;
#pragma unroll
    for (int r = 0; r < 4; ++r) o[r] = f2bf(f[r]);
    *(u16x4*)(xb + (size_t)i * 4) = o;
    return;
  }
  int idx = (bid - 3072) * 256 + threadIdx.x; // < 3072*768
  int n = idx / 768, d = idx - n * 768;
  if (n >= 2304) {
    wob[(n - 2304) * 768 + d] = f2bf(wo[(n - 2304) * 768 + d]);
    return;
  }
  const float *w, *dn, *up; int e;
  if (n < 768)       { w = wq; dn = dq; up = uq; e = n; }
  else if (n < 1536) { w = wk; dn = dk; up = uk; e = n - 768; }
  else               { w = wv; dn = dv; up = uv; e = n - 1536; }
  float acc = w[e * 768 + d];
  float lo = 0.f;
#pragma unroll
  for (int r = 0; r < 8; ++r) lo += up[e * 8 + r] * dn[r * 768 + d];
  weff[idx] = f2bf(acc + 2.0f * lo);   // SCALING = alpha/rank = 2
}

// ---------------- NT GEMM: C[m,n] = sum_k A[m,k]*B[n,k] (+bias) ----------------
// MT x 128 block tile, BK=32, 256 thr. MT=128: 2x2 waves of 64x64. MT=32: 1x4 waves of 32x32.
// mode 0: N=2304 -> q[h][s][64] (pre-scaled by 0.125*log2e), k[h][s][64], vt[h][64][s]
// mode 1: N=768  -> fo[s][768] fp32 (+bo)
template <int MT>
__global__ __launch_bounds__(256) void gemm_nt(
    const u16* __restrict__ A, const u16* __restrict__ B, int K, int mode,
    const float* __restrict__ bq, const float* __restrict__ bk, const float* __restrict__ bv,
    u16* __restrict__ qo, u16* __restrict__ ko, u16* __restrict__ vto,
    const float* __restrict__ bo, float* __restrict__ fo) {
  constexpr int TI = (MT == 128) ? 4 : 2;
  constexpr int TJ = (MT == 128) ? 4 : 2;
  __shared__ u16 As[MT * 32];
  __shared__ u16 Bs[128 * 32];
  const int tid = threadIdx.x;
  const int lane = tid & 63;
  const int wid = tid >> 6;
  const int qd = lane >> 4;
  const int m16 = lane & 15;
  const int rowbase = (MT == 128) ? (wid >> 1) * 64 : 0;
  const int colbase = (MT == 128) ? (wid & 1) * 64 : wid * 32;
  const int m0 = blockIdx.x * MT, n0 = blockIdx.y * 128;

  f32x4 acc[TI][TJ];
#pragma unroll
  for (int i = 0; i < TI; ++i)
#pragma unroll
    for (int j = 0; j < TJ; ++j)
#pragma unroll
      for (int e = 0; e < 4; ++e) acc[i][j][e] = 0.f;

  for (int k0 = 0; k0 < K; k0 += 32) {
    __syncthreads();
#pragma unroll
    for (int p = tid; p < MT * 4; p += 256) {
      int row = p >> 2;
      int g = (p & 3) ^ ((row >> 1) & 3);
      gld16(A + (size_t)(m0 + row) * K + k0 + g * 8, &As[(p - lane) * 8]);
    }
#pragma unroll
    for (int p = tid; p < 512; p += 256) {
      int row = p >> 2;
      int g = (p & 3) ^ ((row >> 1) & 3);
      gld16(B + (size_t)(n0 + row) * K + k0 + g * 8, &Bs[(p - lane) * 8]);
    }
    __syncthreads();
    short8 af[TI], bf[TJ];
#pragma unroll
    for (int i = 0; i < TI; ++i) {
      int ar = rowbase + i * 16 + m16;
      af[i] = *(const short8*)&As[(ar * 4 + (qd ^ ((ar >> 1) & 3))) * 8];
    }
#pragma unroll
    for (int j = 0; j < TJ; ++j) {
      int br = colbase + j * 16 + m16;
      bf[j] = *(const short8*)&Bs[(br * 4 + (qd ^ ((br >> 1) & 3))) * 8];
    }
#pragma unroll
    for (int i = 0; i < TI; ++i)
#pragma unroll
      for (int j = 0; j < TJ; ++j)
        acc[i][j] = __builtin_amdgcn_mfma_f32_16x16x32_bf16(af[i], bf[j], acc[i][j], 0, 0, 0);
  }

  // C/D layout: col = m16, row = qd*4 + reg
#pragma unroll
  for (int i = 0; i < TI; ++i) {
    int gr = m0 + rowbase + i * 16 + qd * 4;
#pragma unroll
    for (int j = 0; j < TJ; ++j) {
      int gc = n0 + colbase + j * 16 + m16;
      if (mode == 0) {
        if (gc < 768) {
          float bias = bq[gc];
          int h = gc >> 6, d = gc & 63;
          // fold attention scale 1/8 and log2(e) into Q: exp(x/8) = exp2(x*0.18034)
#pragma unroll
          for (int r = 0; r < 4; ++r)
            qo[((size_t)h * 4096 + gr + r) * 64 + d] = f2bf((acc[i][j][r] + bias) * 0.18033688f);
        } else if (gc < 1536) {
          int c = gc - 768;
          float bias = bk[c];
          int h = c >> 6, d = c & 63;
#pragma unroll
          for (int r = 0; r < 4; ++r)
            ko[((size_t)h * 4096 + gr + r) * 64 + d] = f2bf(acc[i][j][r] + bias);
        } else {
          int c = gc - 1536;
          float bias = bv[c];
          int h = c >> 6, d = c & 63;
          u16x4 pk;
#pragma unroll
          for (int r = 0; r < 4; ++r) pk[r] = f2bf(acc[i][j][r] + bias);
          *(u16x4*)&vto[((size_t)h * 64 + d) * 4096 + gr] = pk;
        }
      } else {
        float bias = bo[gc];
#pragma unroll
        for (int r = 0; r < 4; ++r)
          fo[(size_t)(gr + r) * 768 + gc] = acc[i][j][r] + bias;
      }
    }
  }
}

// ---------------- flash attention fwd (S^T form, fixed-max base-2 softmax) ----------------
// grid (16 qblocks, 12 heads, kspl), 256 thr / 4 waves. Wave owns 64 q-rows (4 MFMA tiles);
// K/V-frag reads shared across the 4 tiles. k processed in 4 quarters of 32.
// P region per (wave,tile): 16 q-rows x 40 elems (80 B stride, 16B-aligned, pad 8):
//   b128 reads: bank start (20*m16+4*qd)%32 -> uniform 8/bank (conflict-free)
//   b64 writes: (20*q+8*c2+2*qd)%32        -> uniform 4/bank (conflict-free)
// LDS = 16K (Ks) + 16K (Vs) + 20K (Ps) = 52 KB -> 3 blocks/CU = 12 waves/CU.
__global__ __launch_bounds__(256, 3) void attn_fwd(
    const u16* __restrict__ Q, const u16* __restrict__ Kg, const u16* __restrict__ Vt,
    float* __restrict__ Opart, float* __restrict__ lpart, u16* __restrict__ abo, int kspl) {
  __shared__ u16 Ks[128 * 64];
  __shared__ u16 Vs[64 * 128];
  __shared__ u16 Ps[16 * 640];
  const int tid = threadIdx.x, lane = tid & 63, wid = tid >> 6;
  const int qd = lane >> 4, m16 = lane & 15;
  const int h = blockIdx.y;
  const int qrow = blockIdx.x * 256 + wid * 64;
  const int kbase = blockIdx.z * (4096 / kspl);
  const int niter = (4096 / kspl) >> 7;

  short8 qf[4][2];
#pragma unroll
  for (int t = 0; t < 4; ++t) {
    const u16* qb = Q + ((size_t)h * 4096 + qrow + t * 16 + m16) * 64;
    qf[t][0] = *(const short8*)(qb + qd * 8);
    qf[t][1] = *(const short8*)(qb + 32 + qd * 8);
  }

  float lrun[4] = {0.f, 0.f, 0.f, 0.f};
  f32x4 oacc[4][4];
#pragma unroll
  for (int t = 0; t < 4; ++t)
#pragma unroll
    for (int d = 0; d < 4; ++d)
#pragma unroll
      for (int r = 0; r < 4; ++r) oacc[t][d][r] = 0.f;

  u16* pw = &Ps[wid * 4 * 640];

  for (int it = 0; it < niter; ++it) {
    const int kt = kbase + it * 128;
    __syncthreads();                          // prev frag reads done before restage
#pragma unroll
    for (int rr = 0; rr < 4; ++rr) {
      int p = rr * 256 + tid;                 // 0..1023 K chunks
      int krow = p >> 3;
      int kg = (p & 7) ^ (krow & 7);
      gld16(Kg + ((size_t)h * 4096 + kt + krow) * 64 + kg * 8, &Ks[(p - lane) * 8]);
    }
#pragma unroll
    for (int rr = 0; rr < 4; ++rr) {
      int p = rr * 256 + tid;                 // 0..1023 V chunks
      int vd = p >> 4;
      int vg = (p & 15) ^ (vd & 15);
      gld16(Vt + ((size_t)h * 64 + vd) * 4096 + kt + vg * 8, &Vs[(p - lane) * 8]);
    }
    __syncthreads();

#pragma unroll
    for (int qq = 0; qq < 4; ++qq) {          // 32-k quarter
#pragma unroll
      for (int c2 = 0; c2 < 2; ++c2) {
        int c = qq * 2 + c2;
        int kr = c * 16 + m16;
        short8 kf0 = *(const short8*)&Ks[(kr * 8 + (qd ^ (kr & 7))) * 8];
        short8 kf1 = *(const short8*)&Ks[(kr * 8 + ((4 + qd) ^ (kr & 7))) * 8];
#pragma unroll
        for (int t = 0; t < 4; ++t) {
          f32x4 s = {0.f, 0.f, 0.f, 0.f};
          s = __builtin_amdgcn_mfma_f32_16x16x32_bf16(kf0, qf[t][0], s, 0, 0, 0);
          s = __builtin_amdgcn_mfma_f32_16x16x32_bf16(kf1, qf[t][1], s, 0, 0, 0);
          u16x4 pk;
          float lp = 0.f;
#pragma unroll
          for (int r = 0; r < 4; ++r) {
            float p = __builtin_amdgcn_exp2f(s[r]);
            lp += p;
            pk[r] = (u16)((__float_as_uint(p) + 0x8000u) >> 16);   // half-up bf16
          }
          lrun[t] += lp;
          *(u16x4*)&pw[t * 640 + m16 * 40 + c2 * 16 + qd * 4] = pk;
        }
      }
      // O += P V for this quarter (wave-private P; lgkmcnt orders write->read)
      short8 pf[4];
#pragma unroll
      for (int t = 0; t < 4; ++t)
        pf[t] = *(const short8*)&pw[t * 640 + m16 * 40 + qd * 8];
#pragma unroll
      for (int d = 0; d < 4; ++d) {
        int vr = d * 16 + m16;
        int g = qq * 4 + qd;
        short8 vf = *(const short8*)&Vs[(vr * 16 + (g ^ (vr & 15))) * 8];
#pragma unroll
        for (int t = 0; t < 4; ++t)
          oacc[t][d] = __builtin_amdgcn_mfma_f32_16x16x32_bf16(pf[t], vf, oacc[t][d], 0, 0, 0);
      }
    }
  }

  // l: reduce across the 4 quads (once per kernel)
#pragma unroll
  for (int t = 0; t < 4; ++t) {
    lrun[t] += __shfl_xor(lrun[t], 16);
    lrun[t] += __shfl_xor(lrun[t], 32);
  }

  if (kspl > 1) {
#pragma unroll
    for (int t = 0; t < 4; ++t)
      if (lane < 16)
        lpart[((size_t)blockIdx.z * 4096 + qrow + t * 16 + m16) * 12 + h] = lrun[t];
    float* ob = Opart + (size_t)blockIdx.z * 4096 * 768;
#pragma unroll
    for (int t = 0; t < 4; ++t)
#pragma unroll
      for (int d = 0; d < 4; ++d)
#pragma unroll
        for (int r = 0; r < 4; ++r)
          ob[(size_t)(qrow + t * 16 + qd * 4 + r) * 768 + h * 64 + d * 16 + m16] = oacc[t][d][r];
  } else {
#pragma unroll
    for (int t = 0; t < 4; ++t) {
      float li[4];
#pragma unroll
      for (int r = 0; r < 4; ++r) li[r] = 1.0f / __shfl(lrun[t], qd * 4 + r);
#pragma unroll
      for (int d = 0; d < 4; ++d)
#pragma unroll
        for (int r = 0; r < 4; ++r)
          abo[(size_t)(qrow + t * 16 + qd * 4 + r) * 768 + h * 64 + d * 16 + m16] =
              f2bf(oacc[t][d][r] * li[r]);
    }
  }
}

// ---------------- merge ksp k-split partials + normalize -> bf16, x4 ----------------
__global__ void merge_norm(const float* __restrict__ Opart, const float* __restrict__ lpart,
                           u16* __restrict__ abo, int ksp) {
  int i = blockIdx.x * 256 + threadIdx.x;   // < 786432 (4096*768/4)
  int s = i / 192, cq = i - s * 192;
  int h = cq >> 4;                          // (cq*4)>>6
  f32x4 a = {0.f, 0.f, 0.f, 0.f};
  float l = 0.f;
  for (int z = 0; z < ksp; ++z) {
    f32x4 b = *(const f32x4*)(Opart + (size_t)z * 4096 * 768 + (size_t)i * 4);
#pragma unroll
    for (int r = 0; r < 4; ++r) a[r] += b[r];
    l += lpart[((size_t)z * 4096 + s) * 12 + h];
  }
  float rl = 1.0f / l;
  u16x4 o;
#pragma unroll
  for (int r = 0; r < 4; ++r) o[r] = f2bf(a[r] * rl);
  *(u16x4*)(abo + (size_t)i * 4) = o;
}

extern "C" void kernel_launch(void* const* d_in, const int* in_sizes, int n_in,
                              void* d_out, int out_size, void* d_ws, size_t ws_size,
                              hipStream_t stream) {
  const float* x   = (const float*)d_in[0];
  const float* wq  = (const float*)d_in[1];
  const float* bq  = (const float*)d_in[2];
  const float* wk  = (const float*)d_in[3];
  const float* bk  = (const float*)d_in[4];
  const float* wv  = (const float*)d_in[5];
  const float* bv  = (const float*)d_in[6];
  const float* wo  = (const float*)d_in[7];
  const float* bo  = (const float*)d_in[8];
  const float* dq  = (const float*)d_in[9];
  const float* uq  = (const float*)d_in[10];
  const float* dk  = (const float*)d_in[11];
  const float* uk  = (const float*)d_in[12];
  const float* dv  = (const float*)d_in[13];
  const float* uv  = (const float*)d_in[14];
  float* out = (float*)d_out;

  char* ws = (char*)d_ws;
  u16* xb    = (u16*)(ws);                 // 4096*768 bf16 (6291456 B); dead after QKV gemm
  u16* ab    = (u16*)(ws);                 // aliases xb: attn output [4096][768] bf16
  u16* weff  = (u16*)(ws + 6291456);       // 2304*768
  u16* wob   = (u16*)(ws + 9830400);       // 768*768
  u16* qb    = (u16*)(ws + 11010048);      // [12][4096][64]
  u16* kb    = (u16*)(ws + 17301504);      // [12][4096][64]
  u16* vtb   = (u16*)(ws + 23592960);      // [12][64][4096]
  float* Op  = (float*)(ws + 29884416);    // [kspl][4096][768] f32 (<= 50331648 B)
  float* lp  = (float*)(ws + 80216064);    // [kspl][4096][12]  f32 (<= 786432 B) -> end 81002496

  int kspl = 1;
  if (ws_size >= 81002496ull) kspl = 4;
  else if (ws_size >= 55443456ull) {
    kspl = 2;
    lp = (float*)(ws + 55050240);          // pack tighter for the 2-split case
  }

  prep_all<<<12288, 256, 0, stream>>>(x, xb, wq, wk, wv, dq, uq, dk, uk, dv, uv, wo, weff, wob);
  gemm_nt<128><<<dim3(32, 18), 256, 0, stream>>>(xb, weff, 768, 0, bq, bk, bv, qb, kb, vtb,
                                                 nullptr, nullptr);
  attn_fwd<<<dim3(16, 12, kspl), 256, 0, stream>>>(qb, kb, vtb, Op, lp, ab, kspl);
  if (kspl > 1) merge_norm<<<3072, 256, 0, stream>>>(Op, lp, ab, kspl);
  gemm_nt<32><<<dim3(128, 6), 256, 0, stream>>>(ab, wob, 768, 1, nullptr, nullptr, nullptr,
                                                nullptr, nullptr, nullptr, bo, out);
}

// Round 6
// 251.972 us; speedup vs baseline: 2.2266x; 2.2266x over previous
//
#include <hip/hip_runtime.h>

typedef unsigned short u16;
typedef __attribute__((ext_vector_type(8))) short short8;    // 8 bf16 (4 VGPRs)
typedef __attribute__((ext_vector_type(4))) float f32x4;
typedef __attribute__((ext_vector_type(4))) unsigned short u16x4;

typedef __attribute__((address_space(1))) void as1_void;
typedef __attribute__((address_space(3))) void as3_void;

// async global->LDS, 16B per lane; LDS dest = wave-uniform base + lane*16
__device__ __forceinline__ void gld16(const u16* g, u16* l) {
  __builtin_amdgcn_global_load_lds((as1_void*)g, (as3_void*)l, 16, 0, 0);
}

__device__ __forceinline__ u16 f2bf(float f) {
  unsigned u = __float_as_uint(f);
  u += 0x7fffu + ((u >> 16) & 1u);   // RNE
  return (u16)(u >> 16);
}

// ---------------- fused prep: cvt x (x4) + W_eff + cvt wo ----------------
// blocks [0,3072): x cvt vectorized; [3072,12288): weff rows 0..2303, wob rows 2304..3071
__global__ void prep_all(const float* __restrict__ x, u16* __restrict__ xb,
                         const float* __restrict__ wq, const float* __restrict__ wk, const float* __restrict__ wv,
                         const float* __restrict__ dq, const float* __restrict__ uq,
                         const float* __restrict__ dk, const float* __restrict__ uk,
                         const float* __restrict__ dv, const float* __restrict__ uv,
                         const float* __restrict__ wo, u16* __restrict__ weff, u16* __restrict__ wob) {
  int bid = blockIdx.x;
  if (bid < 3072) {
    int i = bid * 256 + threadIdx.x;          // < 786432
    f32x4 f = *(const f32x4*)(x + (size_t)i * 4);
    u16x4 o;
#pragma unroll
    for (int r = 0; r < 4; ++r) o[r] = f2bf(f[r]);
    *(u16x4*)(xb + (size_t)i * 4) = o;
    return;
  }
  int idx = (bid - 3072) * 256 + threadIdx.x; // < 3072*768
  int n = idx / 768, d = idx - n * 768;
  if (n >= 2304) {
    wob[(n - 2304) * 768 + d] = f2bf(wo[(n - 2304) * 768 + d]);
    return;
  }
  const float *w, *dn, *up; int e;
  if (n < 768)       { w = wq; dn = dq; up = uq; e = n; }
  else if (n < 1536) { w = wk; dn = dk; up = uk; e = n - 768; }
  else               { w = wv; dn = dv; up = uv; e = n - 1536; }
  float acc = w[e * 768 + d];
  float lo = 0.f;
#pragma unroll
  for (int r = 0; r < 8; ++r) lo += up[e * 8 + r] * dn[r * 768 + d];
  weff[idx] = f2bf(acc + 2.0f * lo);   // SCALING = alpha/rank = 2
}

// ---------------- NT GEMM: C[m,n] = sum_k A[m,k]*B[n,k] (+bias) ----------------
// MT x 128 block tile, BK=32, 256 thr. MT=128: 2x2 waves of 64x64. MT=32: 1x4 waves of 32x32.
// mode 0: N=2304 -> q[h][s][64] (pre-scaled by 0.125*log2e), k[h][s][64], vt[h][64][s]
// mode 1: N=768  -> fo[s][768] fp32 (+bo)
template <int MT>
__global__ __launch_bounds__(256) void gemm_nt(
    const u16* __restrict__ A, const u16* __restrict__ B, int K, int mode,
    const float* __restrict__ bq, const float* __restrict__ bk, const float* __restrict__ bv,
    u16* __restrict__ qo, u16* __restrict__ ko, u16* __restrict__ vto,
    const float* __restrict__ bo, float* __restrict__ fo) {
  constexpr int TI = (MT == 128) ? 4 : 2;
  constexpr int TJ = (MT == 128) ? 4 : 2;
  __shared__ u16 As[MT * 32];
  __shared__ u16 Bs[128 * 32];
  const int tid = threadIdx.x;
  const int lane = tid & 63;
  const int wid = tid >> 6;
  const int qd = lane >> 4;
  const int m16 = lane & 15;
  const int rowbase = (MT == 128) ? (wid >> 1) * 64 : 0;
  const int colbase = (MT == 128) ? (wid & 1) * 64 : wid * 32;
  const int m0 = blockIdx.x * MT, n0 = blockIdx.y * 128;

  f32x4 acc[TI][TJ];
#pragma unroll
  for (int i = 0; i < TI; ++i)
#pragma unroll
    for (int j = 0; j < TJ; ++j)
#pragma unroll
      for (int e = 0; e < 4; ++e) acc[i][j][e] = 0.f;

  for (int k0 = 0; k0 < K; k0 += 32) {
    __syncthreads();
#pragma unroll
    for (int p = tid; p < MT * 4; p += 256) {
      int row = p >> 2;
      int g = (p & 3) ^ ((row >> 1) & 3);
      gld16(A + (size_t)(m0 + row) * K + k0 + g * 8, &As[(p - lane) * 8]);
    }
#pragma unroll
    for (int p = tid; p < 512; p += 256) {
      int row = p >> 2;
      int g = (p & 3) ^ ((row >> 1) & 3);
      gld16(B + (size_t)(n0 + row) * K + k0 + g * 8, &Bs[(p - lane) * 8]);
    }
    __syncthreads();
    short8 af[TI], bf[TJ];
#pragma unroll
    for (int i = 0; i < TI; ++i) {
      int ar = rowbase + i * 16 + m16;
      af[i] = *(const short8*)&As[(ar * 4 + (qd ^ ((ar >> 1) & 3))) * 8];
    }
#pragma unroll
    for (int j = 0; j < TJ; ++j) {
      int br = colbase + j * 16 + m16;
      bf[j] = *(const short8*)&Bs[(br * 4 + (qd ^ ((br >> 1) & 3))) * 8];
    }
#pragma unroll
    for (int i = 0; i < TI; ++i)
#pragma unroll
      for (int j = 0; j < TJ; ++j)
        acc[i][j] = __builtin_amdgcn_mfma_f32_16x16x32_bf16(af[i], bf[j], acc[i][j], 0, 0, 0);
  }

  // C/D layout: col = m16, row = qd*4 + reg
#pragma unroll
  for (int i = 0; i < TI; ++i) {
    int gr = m0 + rowbase + i * 16 + qd * 4;
#pragma unroll
    for (int j = 0; j < TJ; ++j) {
      int gc = n0 + colbase + j * 16 + m16;
      if (mode == 0) {
        if (gc < 768) {
          float bias = bq[gc];
          int h = gc >> 6, d = gc & 63;
          // fold attention scale 1/8 and log2(e) into Q: exp(x/8) = exp2(x*0.18034)
#pragma unroll
          for (int r = 0; r < 4; ++r)
            qo[((size_t)h * 4096 + gr + r) * 64 + d] = f2bf((acc[i][j][r] + bias) * 0.18033688f);
        } else if (gc < 1536) {
          int c = gc - 768;
          float bias = bk[c];
          int h = c >> 6, d = c & 63;
#pragma unroll
          for (int r = 0; r < 4; ++r)
            ko[((size_t)h * 4096 + gr + r) * 64 + d] = f2bf(acc[i][j][r] + bias);
        } else {
          int c = gc - 1536;
          float bias = bv[c];
          int h = c >> 6, d = c & 63;
          u16x4 pk;
#pragma unroll
          for (int r = 0; r < 4; ++r) pk[r] = f2bf(acc[i][j][r] + bias);
          *(u16x4*)&vto[((size_t)h * 64 + d) * 4096 + gr] = pk;
        }
      } else {
        float bias = bo[gc];
#pragma unroll
        for (int r = 0; r < 4; ++r)
          fo[(size_t)(gr + r) * 768 + gc] = acc[i][j][r] + bias;
      }
    }
  }
}

// ---------------- flash attention fwd (S^T form, fixed-max base-2 softmax) ----------------
// grid (16 qblocks, 12 heads, kspl), 256 thr / 4 waves. Wave owns 64 q-rows (4 MFMA tiles);
// K/V-frag reads shared across the 4 tiles. k processed in 4 quarters of 32.
// P region per (wave,tile): 16 q-rows x 40 elems (80 B stride, 16B-aligned, pad 8):
//   b128 reads: bank start (20*m16+4*qd)%32 -> uniform 8/bank (conflict-free)
//   b64 writes: (20*q+8*c2+2*qd)%32        -> uniform 4/bank (conflict-free)
// LDS = 16K (Ks) + 16K (Vs) + 20K (Ps) = 52 KB -> 3 blocks/CU = 12 waves/CU.
// NOTE: no min-waves-per-EU bound! R4's __launch_bounds__(256,3) split the unified
// VGPR/AGPR budget to 84 arch-VGPRs -> K-loop scratch spill -> ~2 GB/dispatch HBM traffic.
__global__ __launch_bounds__(256) void attn_fwd(
    const u16* __restrict__ Q, const u16* __restrict__ Kg, const u16* __restrict__ Vt,
    float* __restrict__ Opart, float* __restrict__ lpart, u16* __restrict__ abo, int kspl) {
  __shared__ u16 Ks[128 * 64];
  __shared__ u16 Vs[64 * 128];
  __shared__ u16 Ps[16 * 640];
  const int tid = threadIdx.x, lane = tid & 63, wid = tid >> 6;
  const int qd = lane >> 4, m16 = lane & 15;
  const int h = blockIdx.y;
  const int qrow = blockIdx.x * 256 + wid * 64;
  const int kbase = blockIdx.z * (4096 / kspl);
  const int niter = (4096 / kspl) >> 7;

  short8 qf[4][2];
#pragma unroll
  for (int t = 0; t < 4; ++t) {
    const u16* qb = Q + ((size_t)h * 4096 + qrow + t * 16 + m16) * 64;
    qf[t][0] = *(const short8*)(qb + qd * 8);
    qf[t][1] = *(const short8*)(qb + 32 + qd * 8);
  }

  float lrun[4] = {0.f, 0.f, 0.f, 0.f};
  f32x4 oacc[4][4];
#pragma unroll
  for (int t = 0; t < 4; ++t)
#pragma unroll
    for (int d = 0; d < 4; ++d)
#pragma unroll
      for (int r = 0; r < 4; ++r) oacc[t][d][r] = 0.f;

  u16* pw = &Ps[wid * 4 * 640];

  for (int it = 0; it < niter; ++it) {
    const int kt = kbase + it * 128;
    __syncthreads();                          // prev frag reads done before restage
#pragma unroll
    for (int rr = 0; rr < 4; ++rr) {
      int p = rr * 256 + tid;                 // 0..1023 K chunks
      int krow = p >> 3;
      int kg = (p & 7) ^ (krow & 7);
      gld16(Kg + ((size_t)h * 4096 + kt + krow) * 64 + kg * 8, &Ks[(p - lane) * 8]);
    }
#pragma unroll
    for (int rr = 0; rr < 4; ++rr) {
      int p = rr * 256 + tid;                 // 0..1023 V chunks
      int vd = p >> 4;
      int vg = (p & 15) ^ (vd & 15);
      gld16(Vt + ((size_t)h * 64 + vd) * 4096 + kt + vg * 8, &Vs[(p - lane) * 8]);
    }
    __syncthreads();

#pragma unroll
    for (int qq = 0; qq < 4; ++qq) {          // 32-k quarter
#pragma unroll
      for (int c2 = 0; c2 < 2; ++c2) {
        int c = qq * 2 + c2;
        int kr = c * 16 + m16;
        short8 kf0 = *(const short8*)&Ks[(kr * 8 + (qd ^ (kr & 7))) * 8];
        short8 kf1 = *(const short8*)&Ks[(kr * 8 + ((4 + qd) ^ (kr & 7))) * 8];
#pragma unroll
        for (int t = 0; t < 4; ++t) {
          f32x4 s = {0.f, 0.f, 0.f, 0.f};
          s = __builtin_amdgcn_mfma_f32_16x16x32_bf16(kf0, qf[t][0], s, 0, 0, 0);
          s = __builtin_amdgcn_mfma_f32_16x16x32_bf16(kf1, qf[t][1], s, 0, 0, 0);
          u16x4 pk;
          float lp = 0.f;
#pragma unroll
          for (int r = 0; r < 4; ++r) {
            float p = __builtin_amdgcn_exp2f(s[r]);
            lp += p;
            pk[r] = (u16)((__float_as_uint(p) + 0x8000u) >> 16);   // half-up bf16
          }
          lrun[t] += lp;
          *(u16x4*)&pw[t * 640 + m16 * 40 + c2 * 16 + qd * 4] = pk;
        }
      }
      // O += P V for this quarter (wave-private P; lgkmcnt orders write->read)
      short8 pf[4];
#pragma unroll
      for (int t = 0; t < 4; ++t)
        pf[t] = *(const short8*)&pw[t * 640 + m16 * 40 + qd * 8];
#pragma unroll
      for (int d = 0; d < 4; ++d) {
        int vr = d * 16 + m16;
        int g = qq * 4 + qd;
        short8 vf = *(const short8*)&Vs[(vr * 16 + (g ^ (vr & 15))) * 8];
#pragma unroll
        for (int t = 0; t < 4; ++t)
          oacc[t][d] = __builtin_amdgcn_mfma_f32_16x16x32_bf16(pf[t], vf, oacc[t][d], 0, 0, 0);
      }
    }
  }

  // l: reduce across the 4 quads (once per kernel)
#pragma unroll
  for (int t = 0; t < 4; ++t) {
    lrun[t] += __shfl_xor(lrun[t], 16);
    lrun[t] += __shfl_xor(lrun[t], 32);
  }

  if (kspl > 1) {
#pragma unroll
    for (int t = 0; t < 4; ++t)
      if (lane < 16)
        lpart[((size_t)blockIdx.z * 4096 + qrow + t * 16 + m16) * 12 + h] = lrun[t];
    float* ob = Opart + (size_t)blockIdx.z * 4096 * 768;
#pragma unroll
    for (int t = 0; t < 4; ++t)
#pragma unroll
      for (int d = 0; d < 4; ++d)
#pragma unroll
        for (int r = 0; r < 4; ++r)
          ob[(size_t)(qrow + t * 16 + qd * 4 + r) * 768 + h * 64 + d * 16 + m16] = oacc[t][d][r];
  } else {
#pragma unroll
    for (int t = 0; t < 4; ++t) {
      float li[4];
#pragma unroll
      for (int r = 0; r < 4; ++r) li[r] = 1.0f / __shfl(lrun[t], qd * 4 + r);
#pragma unroll
      for (int d = 0; d < 4; ++d)
#pragma unroll
        for (int r = 0; r < 4; ++r)
          abo[(size_t)(qrow + t * 16 + qd * 4 + r) * 768 + h * 64 + d * 16 + m16] =
              f2bf(oacc[t][d][r] * li[r]);
    }
  }
}

// ---------------- merge ksp k-split partials + normalize -> bf16, x4 ----------------
__global__ void merge_norm(const float* __restrict__ Opart, const float* __restrict__ lpart,
                           u16* __restrict__ abo, int ksp) {
  int i = blockIdx.x * 256 + threadIdx.x;   // < 786432 (4096*768/4)
  int s = i / 192, cq = i - s * 192;
  int h = cq >> 4;                          // (cq*4)>>6
  f32x4 a = {0.f, 0.f, 0.f, 0.f};
  float l = 0.f;
  for (int z = 0; z < ksp; ++z) {
    f32x4 b = *(const f32x4*)(Opart + (size_t)z * 4096 * 768 + (size_t)i * 4);
#pragma unroll
    for (int r = 0; r < 4; ++r) a[r] += b[r];
    l += lpart[((size_t)z * 4096 + s) * 12 + h];
  }
  float rl = 1.0f / l;
  u16x4 o;
#pragma unroll
  for (int r = 0; r < 4; ++r) o[r] = f2bf(a[r] * rl);
  *(u16x4*)(abo + (size_t)i * 4) = o;
}

extern "C" void kernel_launch(void* const* d_in, const int* in_sizes, int n_in,
                              void* d_out, int out_size, void* d_ws, size_t ws_size,
                              hipStream_t stream) {
  const float* x   = (const float*)d_in[0];
  const float* wq  = (const float*)d_in[1];
  const float* bq  = (const float*)d_in[2];
  const float* wk  = (const float*)d_in[3];
  const float* bk  = (const float*)d_in[4];
  const float* wv  = (const float*)d_in[5];
  const float* bv  = (const float*)d_in[6];
  const float* wo  = (const float*)d_in[7];
  const float* bo  = (const float*)d_in[8];
  const float* dq  = (const float*)d_in[9];
  const float* uq  = (const float*)d_in[10];
  const float* dk  = (const float*)d_in[11];
  const float* uk  = (const float*)d_in[12];
  const float* dv  = (const float*)d_in[13];
  const float* uv  = (const float*)d_in[14];
  float* out = (float*)d_out;

  char* ws = (char*)d_ws;
  u16* xb    = (u16*)(ws);                 // 4096*768 bf16 (6291456 B); dead after QKV gemm
  u16* ab    = (u16*)(ws);                 // aliases xb: attn output [4096][768] bf16
  u16* weff  = (u16*)(ws + 6291456);       // 2304*768
  u16* wob   = (u16*)(ws + 9830400);       // 768*768
  u16* qb    = (u16*)(ws + 11010048);      // [12][4096][64]
  u16* kb    = (u16*)(ws + 17301504);      // [12][4096][64]
  u16* vtb   = (u16*)(ws + 23592960);      // [12][64][4096]
  float* Op  = (float*)(ws + 29884416);    // [kspl][4096][768] f32 (<= 50331648 B)
  float* lp  = (float*)(ws + 80216064);    // [kspl][4096][12]  f32 (<= 786432 B) -> end 81002496

  int kspl = 1;
  if (ws_size >= 81002496ull) kspl = 4;
  else if (ws_size >= 55443456ull) {
    kspl = 2;
    lp = (float*)(ws + 55050240);          // pack tighter for the 2-split case
  }

  prep_all<<<12288, 256, 0, stream>>>(x, xb, wq, wk, wv, dq, uq, dk, uk, dv, uv, wo, weff, wob);
  gemm_nt<128><<<dim3(32, 18), 256, 0, stream>>>(xb, weff, 768, 0, bq, bk, bv, qb, kb, vtb,
                                                 nullptr, nullptr);
  attn_fwd<<<dim3(16, 12, kspl), 256, 0, stream>>>(qb, kb, vtb, Op, lp, ab, kspl);
  if (kspl > 1) merge_norm<<<3072, 256, 0, stream>>>(Op, lp, ab, kspl);
  gemm_nt<32><<<dim3(128, 6), 256, 0, stream>>>(ab, wob, 768, 1, nullptr, nullptr, nullptr,
                                                nullptr, nullptr, nullptr, bo, out);
}

// Round 7
// 235.162 us; speedup vs baseline: 2.3858x; 1.0715x over previous
//
#include <hip/hip_runtime.h>

typedef unsigned short u16;
typedef __attribute__((ext_vector_type(8))) short short8;    // 8 bf16 (4 VGPRs)
typedef __attribute__((ext_vector_type(4))) float f32x4;
typedef __attribute__((ext_vector_type(4))) unsigned short u16x4;

typedef __attribute__((address_space(1))) void as1_void;
typedef __attribute__((address_space(3))) void as3_void;

// async global->LDS, 16B per lane; LDS dest = wave-uniform base + lane*16
__device__ __forceinline__ void gld16(const u16* g, u16* l) {
  __builtin_amdgcn_global_load_lds((as1_void*)g, (as3_void*)l, 16, 0, 0);
}

__device__ __forceinline__ u16 f2bf(float f) {
  unsigned u = __float_as_uint(f);
  u += 0x7fffu + ((u >> 16) & 1u);   // RNE
  return (u16)(u >> 16);
}

// ---------------- fused prep: cvt x (x4) + W_eff + cvt wo ----------------
// blocks [0,3072): x cvt vectorized; [3072,12288): weff rows 0..2303, wob rows 2304..3071
__global__ void prep_all(const float* __restrict__ x, u16* __restrict__ xb,
                         const float* __restrict__ wq, const float* __restrict__ wk, const float* __restrict__ wv,
                         const float* __restrict__ dq, const float* __restrict__ uq,
                         const float* __restrict__ dk, const float* __restrict__ uk,
                         const float* __restrict__ dv, const float* __restrict__ uv,
                         const float* __restrict__ wo, u16* __restrict__ weff, u16* __restrict__ wob) {
  int bid = blockIdx.x;
  if (bid < 3072) {
    int i = bid * 256 + threadIdx.x;          // < 786432
    f32x4 f = *(const f32x4*)(x + (size_t)i * 4);
    u16x4 o;
#pragma unroll
    for (int r = 0; r < 4; ++r) o[r] = f2bf(f[r]);
    *(u16x4*)(xb + (size_t)i * 4) = o;
    return;
  }
  int idx = (bid - 3072) * 256 + threadIdx.x; // < 3072*768
  int n = idx / 768, d = idx - n * 768;
  if (n >= 2304) {
    wob[(n - 2304) * 768 + d] = f2bf(wo[(n - 2304) * 768 + d]);
    return;
  }
  const float *w, *dn, *up; int e;
  if (n < 768)       { w = wq; dn = dq; up = uq; e = n; }
  else if (n < 1536) { w = wk; dn = dk; up = uk; e = n - 768; }
  else               { w = wv; dn = dv; up = uv; e = n - 1536; }
  float acc = w[e * 768 + d];
  float lo = 0.f;
#pragma unroll
  for (int r = 0; r < 8; ++r) lo += up[e * 8 + r] * dn[r * 768 + d];
  weff[idx] = f2bf(acc + 2.0f * lo);   // SCALING = alpha/rank = 2
}

// ---------------- NT GEMM: C[m,n] = sum_k A[m,k]*B[n,k] (+bias) ----------------
// MT x 128 block tile, BK=32, 256 thr. MT=128: 2x2 waves of 64x64. MT=32: 1x4 waves of 32x32.
// mode 0: N=2304 -> q[h][s][64] (pre-scaled by 0.125*log2e), k[h][s][64], vt[h][64][s]
// mode 1: N=768  -> fo[s][768] fp32 (+bo)
template <int MT>
__global__ __launch_bounds__(256) void gemm_nt(
    const u16* __restrict__ A, const u16* __restrict__ B, int K, int mode,
    const float* __restrict__ bq, const float* __restrict__ bk, const float* __restrict__ bv,
    u16* __restrict__ qo, u16* __restrict__ ko, u16* __restrict__ vto,
    const float* __restrict__ bo, float* __restrict__ fo) {
  constexpr int TI = (MT == 128) ? 4 : 2;
  constexpr int TJ = (MT == 128) ? 4 : 2;
  __shared__ u16 As[MT * 32];
  __shared__ u16 Bs[128 * 32];
  const int tid = threadIdx.x;
  const int lane = tid & 63;
  const int wid = tid >> 6;
  const int qd = lane >> 4;
  const int m16 = lane & 15;
  const int rowbase = (MT == 128) ? (wid >> 1) * 64 : 0;
  const int colbase = (MT == 128) ? (wid & 1) * 64 : wid * 32;
  const int m0 = blockIdx.x * MT, n0 = blockIdx.y * 128;

  f32x4 acc[TI][TJ];
#pragma unroll
  for (int i = 0; i < TI; ++i)
#pragma unroll
    for (int j = 0; j < TJ; ++j)
#pragma unroll
      for (int e = 0; e < 4; ++e) acc[i][j][e] = 0.f;

  for (int k0 = 0; k0 < K; k0 += 32) {
    __syncthreads();
#pragma unroll
    for (int p = tid; p < MT * 4; p += 256) {
      int row = p >> 2;
      int g = (p & 3) ^ ((row >> 1) & 3);
      gld16(A + (size_t)(m0 + row) * K + k0 + g * 8, &As[(p - lane) * 8]);
    }
#pragma unroll
    for (int p = tid; p < 512; p += 256) {
      int row = p >> 2;
      int g = (p & 3) ^ ((row >> 1) & 3);
      gld16(B + (size_t)(n0 + row) * K + k0 + g * 8, &Bs[(p - lane) * 8]);
    }
    __syncthreads();
    short8 af[TI], bf[TJ];
#pragma unroll
    for (int i = 0; i < TI; ++i) {
      int ar = rowbase + i * 16 + m16;
      af[i] = *(const short8*)&As[(ar * 4 + (qd ^ ((ar >> 1) & 3))) * 8];
    }
#pragma unroll
    for (int j = 0; j < TJ; ++j) {
      int br = colbase + j * 16 + m16;
      bf[j] = *(const short8*)&Bs[(br * 4 + (qd ^ ((br >> 1) & 3))) * 8];
    }
#pragma unroll
    for (int i = 0; i < TI; ++i)
#pragma unroll
      for (int j = 0; j < TJ; ++j)
        acc[i][j] = __builtin_amdgcn_mfma_f32_16x16x32_bf16(af[i], bf[j], acc[i][j], 0, 0, 0);
  }

  // C/D layout: col = m16, row = qd*4 + reg
#pragma unroll
  for (int i = 0; i < TI; ++i) {
    int gr = m0 + rowbase + i * 16 + qd * 4;
#pragma unroll
    for (int j = 0; j < TJ; ++j) {
      int gc = n0 + colbase + j * 16 + m16;
      if (mode == 0) {
        if (gc < 768) {
          float bias = bq[gc];
          int h = gc >> 6, d = gc & 63;
          // fold attention scale 1/8 and log2(e) into Q: exp(x/8) = exp2(x*0.18034)
#pragma unroll
          for (int r = 0; r < 4; ++r)
            qo[((size_t)h * 4096 + gr + r) * 64 + d] = f2bf((acc[i][j][r] + bias) * 0.18033688f);
        } else if (gc < 1536) {
          int c = gc - 768;
          float bias = bk[c];
          int h = c >> 6, d = c & 63;
#pragma unroll
          for (int r = 0; r < 4; ++r)
            ko[((size_t)h * 4096 + gr + r) * 64 + d] = f2bf(acc[i][j][r] + bias);
        } else {
          int c = gc - 1536;
          float bias = bv[c];
          int h = c >> 6, d = c & 63;
          u16x4 pk;
#pragma unroll
          for (int r = 0; r < 4; ++r) pk[r] = f2bf(acc[i][j][r] + bias);
          *(u16x4*)&vto[((size_t)h * 64 + d) * 4096 + gr] = pk;
        }
      } else {
        float bias = bo[gc];
#pragma unroll
        for (int r = 0; r < 4; ++r)
          fo[(size_t)(gr + r) * 768 + gc] = acc[i][j][r] + bias;
      }
    }
  }
}

// ---------------- flash attention fwd (S^T form, fixed-max base-2 softmax) ----------------
// grid (16 qblocks, 12 heads, kspl), 256 thr / 4 waves. Wave owns 64 q-rows (4 MFMA tiles).
// k-tile = 64, DOUBLE-BUFFERED K/V staging with ONE barrier per iter:
//   barrier -> issue gld16 for it+1 into buf^1 (no wait) -> compute it from buf.
// The barrier's vmcnt(0) drain lands ~2000 compute-cycles after issue -> HBM latency hidden
// (R5's stage->barrier->compute exposed ~900 cyc latency every iter; all pipes <31% busy).
// K buf 64x64 (8 chunks/row, phys = row*8 + (g ^ (row&7))); V^T buf 64d x 64k same swizzle.
// P region per (wave,tile): 16 q x 40 elems (80 B stride) -> uniform banks on b64 write/b128 read.
// LDS = 2*8K (Ks) + 2*8K (Vs) + 20K (Ps) = 52 KB -> 3 blocks/CU; VGPR ~132 -> 3 waves/SIMD.
__global__ __launch_bounds__(256) void attn_fwd(
    const u16* __restrict__ Q, const u16* __restrict__ Kg, const u16* __restrict__ Vt,
    float* __restrict__ Opart, float* __restrict__ lpart, u16* __restrict__ abo, int kspl) {
  __shared__ u16 Ks[2][64 * 64];
  __shared__ u16 Vs[2][64 * 64];
  __shared__ u16 Ps[16 * 640];
  const int tid = threadIdx.x, lane = tid & 63, wid = tid >> 6;
  const int qd = lane >> 4, m16 = lane & 15;
  const int h = blockIdx.y;
  const int qrow = blockIdx.x * 256 + wid * 64;
  const int kbase = blockIdx.z * (4096 / kspl);
  const int niter = (4096 / kspl) >> 6;

  short8 qf[4][2];
#pragma unroll
  for (int t = 0; t < 4; ++t) {
    const u16* qb = Q + ((size_t)h * 4096 + qrow + t * 16 + m16) * 64;
    qf[t][0] = *(const short8*)(qb + qd * 8);
    qf[t][1] = *(const short8*)(qb + 32 + qd * 8);
  }

  float lrun[4] = {0.f, 0.f, 0.f, 0.f};
  f32x4 oacc[4][4];
#pragma unroll
  for (int t = 0; t < 4; ++t)
#pragma unroll
    for (int d = 0; d < 4; ++d)
#pragma unroll
      for (int r = 0; r < 4; ++r) oacc[t][d][r] = 0.f;

  u16* pw = &Ps[wid * 4 * 640];
  const u16* kgh = Kg + (size_t)h * 4096 * 64;
  const u16* vth = Vt + (size_t)h * 64 * 4096;

  // prologue: stage iter 0 into buffer 0
  {
    const int kt = kbase;
#pragma unroll
    for (int rr = 0; rr < 2; ++rr) {
      int p = rr * 256 + tid;                 // 0..511 chunks
      int row = p >> 3;
      int g = (p & 7) ^ (row & 7);
      gld16(kgh + (size_t)(kt + row) * 64 + g * 8, &Ks[0][(p - lane) * 8]);
      gld16(vth + (size_t)row * 4096 + kt + g * 8, &Vs[0][(p - lane) * 8]);
    }
  }

  for (int it = 0; it < niter; ++it) {
    __syncthreads();   // buf[it&1] staged (issued last iter); prev reads of buf^1 done
    if (it + 1 < niter) {
      const int kt = kbase + (it + 1) * 64;
      const int b = (it + 1) & 1;
#pragma unroll
      for (int rr = 0; rr < 2; ++rr) {
        int p = rr * 256 + tid;
        int row = p >> 3;
        int g = (p & 7) ^ (row & 7);
        gld16(kgh + (size_t)(kt + row) * 64 + g * 8, &Ks[b][(p - lane) * 8]);
        gld16(vth + (size_t)row * 4096 + kt + g * 8, &Vs[b][(p - lane) * 8]);
      }
    }
    const u16* ks = Ks[it & 1];
    const u16* vs = Vs[it & 1];

#pragma unroll
    for (int qq = 0; qq < 2; ++qq) {          // 32-k quarter
#pragma unroll
      for (int c2 = 0; c2 < 2; ++c2) {
        int c = qq * 2 + c2;
        int kr = c * 16 + m16;
        short8 kf0 = *(const short8*)&ks[(kr * 8 + (qd ^ (kr & 7))) * 8];
        short8 kf1 = *(const short8*)&ks[(kr * 8 + ((4 + qd) ^ (kr & 7))) * 8];
#pragma unroll
        for (int t = 0; t < 4; ++t) {
          f32x4 s = {0.f, 0.f, 0.f, 0.f};
          s = __builtin_amdgcn_mfma_f32_16x16x32_bf16(kf0, qf[t][0], s, 0, 0, 0);
          s = __builtin_amdgcn_mfma_f32_16x16x32_bf16(kf1, qf[t][1], s, 0, 0, 0);
          u16x4 pk;
          float lp = 0.f;
#pragma unroll
          for (int r = 0; r < 4; ++r) {
            float p = __builtin_amdgcn_exp2f(s[r]);
            lp += p;
            pk[r] = (u16)((__float_as_uint(p) + 0x8000u) >> 16);   // half-up bf16
          }
          lrun[t] += lp;
          *(u16x4*)&pw[t * 640 + m16 * 40 + c2 * 16 + qd * 4] = pk;
        }
      }
      // O += P V for this quarter (wave-private P; lgkmcnt orders write->read)
      short8 pf[4];
#pragma unroll
      for (int t = 0; t < 4; ++t)
        pf[t] = *(const short8*)&pw[t * 640 + m16 * 40 + qd * 8];
#pragma unroll
      for (int d = 0; d < 4; ++d) {
        int vr = d * 16 + m16;
        int g = qq * 4 + qd;
        short8 vf = *(const short8*)&vs[(vr * 8 + (g ^ (vr & 7))) * 8];
#pragma unroll
        for (int t = 0; t < 4; ++t)
          oacc[t][d] = __builtin_amdgcn_mfma_f32_16x16x32_bf16(pf[t], vf, oacc[t][d], 0, 0, 0);
      }
    }
  }

  // l: reduce across the 4 quads (once per kernel)
#pragma unroll
  for (int t = 0; t < 4; ++t) {
    lrun[t] += __shfl_xor(lrun[t], 16);
    lrun[t] += __shfl_xor(lrun[t], 32);
  }

  if (kspl > 1) {
#pragma unroll
    for (int t = 0; t < 4; ++t)
      if (lane < 16)
        lpart[((size_t)blockIdx.z * 4096 + qrow + t * 16 + m16) * 12 + h] = lrun[t];
    float* ob = Opart + (size_t)blockIdx.z * 4096 * 768;
#pragma unroll
    for (int t = 0; t < 4; ++t)
#pragma unroll
      for (int d = 0; d < 4; ++d)
#pragma unroll
        for (int r = 0; r < 4; ++r)
          ob[(size_t)(qrow + t * 16 + qd * 4 + r) * 768 + h * 64 + d * 16 + m16] = oacc[t][d][r];
  } else {
#pragma unroll
    for (int t = 0; t < 4; ++t) {
      float li[4];
#pragma unroll
      for (int r = 0; r < 4; ++r) li[r] = 1.0f / __shfl(lrun[t], qd * 4 + r);
#pragma unroll
      for (int d = 0; d < 4; ++d)
#pragma unroll
        for (int r = 0; r < 4; ++r)
          abo[(size_t)(qrow + t * 16 + qd * 4 + r) * 768 + h * 64 + d * 16 + m16] =
              f2bf(oacc[t][d][r] * li[r]);
    }
  }
}

// ---------------- merge ksp k-split partials + normalize -> bf16, x4 ----------------
__global__ void merge_norm(const float* __restrict__ Opart, const float* __restrict__ lpart,
                           u16* __restrict__ abo, int ksp) {
  int i = blockIdx.x * 256 + threadIdx.x;   // < 786432 (4096*768/4)
  int s = i / 192, cq = i - s * 192;
  int h = cq >> 4;                          // (cq*4)>>6
  f32x4 a = {0.f, 0.f, 0.f, 0.f};
  float l = 0.f;
  for (int z = 0; z < ksp; ++z) {
    f32x4 b = *(const f32x4*)(Opart + (size_t)z * 4096 * 768 + (size_t)i * 4);
#pragma unroll
    for (int r = 0; r < 4; ++r) a[r] += b[r];
    l += lpart[((size_t)z * 4096 + s) * 12 + h];
  }
  float rl = 1.0f / l;
  u16x4 o;
#pragma unroll
  for (int r = 0; r < 4; ++r) o[r] = f2bf(a[r] * rl);
  *(u16x4*)(abo + (size_t)i * 4) = o;
}

extern "C" void kernel_launch(void* const* d_in, const int* in_sizes, int n_in,
                              void* d_out, int out_size, void* d_ws, size_t ws_size,
                              hipStream_t stream) {
  const float* x   = (const float*)d_in[0];
  const float* wq  = (const float*)d_in[1];
  const float* bq  = (const float*)d_in[2];
  const float* wk  = (const float*)d_in[3];
  const float* bk  = (const float*)d_in[4];
  const float* wv  = (const float*)d_in[5];
  const float* bv  = (const float*)d_in[6];
  const float* wo  = (const float*)d_in[7];
  const float* bo  = (const float*)d_in[8];
  const float* dq  = (const float*)d_in[9];
  const float* uq  = (const float*)d_in[10];
  const float* dk  = (const float*)d_in[11];
  const float* uk  = (const float*)d_in[12];
  const float* dv  = (const float*)d_in[13];
  const float* uv  = (const float*)d_in[14];
  float* out = (float*)d_out;

  char* ws = (char*)d_ws;
  u16* xb    = (u16*)(ws);                 // 4096*768 bf16 (6291456 B); dead after QKV gemm
  u16* ab    = (u16*)(ws);                 // aliases xb: attn output [4096][768] bf16
  u16* weff  = (u16*)(ws + 6291456);       // 2304*768
  u16* wob   = (u16*)(ws + 9830400);       // 768*768
  u16* qb    = (u16*)(ws + 11010048);      // [12][4096][64]
  u16* kb    = (u16*)(ws + 17301504);      // [12][4096][64]
  u16* vtb   = (u16*)(ws + 23592960);      // [12][64][4096]
  float* Op  = (float*)(ws + 29884416);    // [kspl][4096][768] f32 (<= 50331648 B)
  float* lp  = (float*)(ws + 80216064);    // [kspl][4096][12]  f32 (<= 786432 B) -> end 81002496

  int kspl = 1;
  if (ws_size >= 81002496ull) kspl = 4;
  else if (ws_size >= 55443456ull) {
    kspl = 2;
    lp = (float*)(ws + 55050240);          // pack tighter for the 2-split case
  }

  prep_all<<<12288, 256, 0, stream>>>(x, xb, wq, wk, wv, dq, uq, dk, uk, dv, uv, wo, weff, wob);
  gemm_nt<128><<<dim3(32, 18), 256, 0, stream>>>(xb, weff, 768, 0, bq, bk, bv, qb, kb, vtb,
                                                 nullptr, nullptr);
  attn_fwd<<<dim3(16, 12, kspl), 256, 0, stream>>>(qb, kb, vtb, Op, lp, ab, kspl);
  if (kspl > 1) merge_norm<<<3072, 256, 0, stream>>>(Op, lp, ab, kspl);
  gemm_nt<32><<<dim3(128, 6), 256, 0, stream>>>(ab, wob, 768, 1, nullptr, nullptr, nullptr,
                                                nullptr, nullptr, nullptr, bo, out);
}